// Round 1
// baseline (104.517 us; speedup 1.0000x reference)
//
#include <hip/hip_runtime.h>

// DotProductIncident: out[e] = dot(nf[src[e]], nf[dst[e]]), D=64, fp32.
// 16 lanes per edge: lane loads float4 from each row (coalesced 256B/row
// per 16-lane group), 4-step shfl_xor reduce, lane 0 writes.

constexpr int D_FEAT = 64;

__global__ __launch_bounds__(256) void edge_dot_kernel(
    const float* __restrict__ nf,
    const int* __restrict__ esrc,
    const int* __restrict__ edst,
    float* __restrict__ out,
    int n_edges)
{
    const int tid  = blockIdx.x * blockDim.x + threadIdx.x;
    const int sub  = threadIdx.x & 15;            // lane within 16-group
    const int gcnt = (gridDim.x * blockDim.x) >> 4;  // total 16-lane groups

    for (int e = tid >> 4; e < n_edges; e += gcnt) {
        const int s = esrc[e];
        const int d = edst[e];
        const float4 a = *reinterpret_cast<const float4*>(nf + (size_t)s * D_FEAT + sub * 4);
        const float4 b = *reinterpret_cast<const float4*>(nf + (size_t)d * D_FEAT + sub * 4);
        float p = a.x * b.x + a.y * b.y + a.z * b.z + a.w * b.w;
        // reduce across the 16-lane group (xor masks < 16 stay in-group)
        p += __shfl_xor(p, 8);
        p += __shfl_xor(p, 4);
        p += __shfl_xor(p, 2);
        p += __shfl_xor(p, 1);
        if (sub == 0) out[e] = p;
    }
}

extern "C" void kernel_launch(void* const* d_in, const int* in_sizes, int n_in,
                              void* d_out, int out_size, void* d_ws, size_t ws_size,
                              hipStream_t stream)
{
    const float* nf   = (const float*)d_in[0];
    const int*   esrc = (const int*)d_in[1];
    const int*   edst = (const int*)d_in[2];
    float*       out  = (float*)d_out;
    const int n_edges = in_sizes[1];

    const int block = 256;
    // 16 lanes/edge -> need n_edges*16 threads total; grid-stride, cap at
    // full-occupancy resident set (256 CU * 2048 thr / 256 = 2048 blocks).
    long long need = ((long long)n_edges * 16 + block - 1) / block;
    int grid = (int)(need < 2048 ? need : 2048);
    edge_dot_kernel<<<grid, block, 0, stream>>>(nf, esrc, edst, out, n_edges);
}